// Round 3
// baseline (249.428 us; speedup 1.0000x reference)
//
#include <hip/hip_runtime.h>

// PatchShuffle: B=64 batches, 16x64 patch grid, stripe width 48, C=768.
// Outputs (concatenated float32 in d_out):
//   visible      : (256, 64, 768)  = 12,582,912 elems
//   fwd          : (1024, 64)      =     65,536 elems (int values as float)
//   bwd          : (1024, 64)      =     65,536 elems
//   stripe_bounds: (2, 64)         =        128 elems
// total out_size = 12,714,112
//
// Division-free layout: block = 192 threads (3 waves) = one float4 row (C4=192).
// Vis blocks each copy 4 rows; b is wave-uniform per row -> start_cols[b] is a
// scalar load. Index tail written as float4 (ranges are all multiples of 4).

#define NROWS     16
#define NCOLS     64
#define NB        64
#define NC        768
#define SW        48
#define NVIS_COLS (NCOLS - SW)          // 16
#define MIN_VIS   (NROWS * NVIS_COLS)   // 256
#define VIS_ELEMS (MIN_VIS * NB * NC)   // 12,582,912
#define TBC       (NROWS * NCOLS)       // 1024
#define C4        (NC / 4)              // 192 float4 per row
#define NFWD      (TBC * NB)            // 65,536
#define NTOT_IDX  (2 * NFWD + 2 * NB)   // 131,200
#define NIDX4     (NTOT_IDX / 4)        // 32,800 float4
#define VIS_ROWS  (MIN_VIS * NB)        // 16,384 rows of 192 float4
#define ROWS_PER_BLOCK 4
#define VIS_BLOCKS (VIS_ROWS / ROWS_PER_BLOCK)            // 4,096
#define IDX_BLOCKS ((NIDX4 + 191) / 192)                  // 171
#define TOTAL_BLOCKS (VIS_BLOCKS + IDX_BLOCKS)            // 4,267

// perm[j] for start s (s in [0,16]): non-stripe cols ascending, then stripe cols.
__device__ __forceinline__ int permcol(int s, int j) {
    return (j < NVIS_COLS) ? ((j < s) ? j : j + SW) : (s + j - NVIS_COLS);
}
// inverse: column c -> position j  (valid for s in [0,16], SW=48)
__device__ __forceinline__ int invcol(int s, int c) {
    return (c < s) ? c : ((c >= s + SW) ? (c - SW) : (c - s + NVIS_COLS));
}

__global__ __launch_bounds__(192) void patchshuffle_kernel(
        const float4* __restrict__ patches,    // (1024*64, 192) float4
        const int*    __restrict__ start_cols,
        float*        __restrict__ out) {
    const int tid = threadIdx.x;               // 0..191 = c4
    const int blk = blockIdx.x;

    if (blk < VIS_BLOCKS) {
        float4* __restrict__ vis = (float4*)out;
        const int ib0 = blk * ROWS_PER_BLOCK;
#pragma unroll
        for (int j = 0; j < ROWS_PER_BLOCK; ++j) {
            const int ib = ib0 + j;            // i*64 + b, 0..16383
            const int i  = ib >> 6;            // 0..255
            const int b  = ib & (NB - 1);      // wave-uniform
            const int s  = start_cols[b];      // scalar load
            const int col   = permcol(s, i & (NCOLS - 1));
            const int src_t = (i & ~(NCOLS - 1)) + col;
            vis[ib * C4 + tid] = patches[(src_t * NB + b) * C4 + tid];
        }
    } else {
        float4* __restrict__ idx4 = (float4*)(out + VIS_ELEMS);
        const int f = (blk - VIS_BLOCKS) * 192 + tid;   // float4 index
        if (f >= NIDX4) return;
        const int e0 = f * 4;                  // element index, multiple of 4
        float4 v;
        if (e0 < NFWD) {                       // fwd[t][b] = (t/64)*64 + perm[t%64]
            const int t = e0 >> 6, b0 = e0 & (NB - 1);
            const int base = t & ~(NCOLS - 1), tj = t & (NCOLS - 1);
            v.x = (float)(base + permcol(start_cols[b0 + 0], tj));
            v.y = (float)(base + permcol(start_cols[b0 + 1], tj));
            v.z = (float)(base + permcol(start_cols[b0 + 2], tj));
            v.w = (float)(base + permcol(start_cols[b0 + 3], tj));
        } else if (e0 < 2 * NFWD) {            // bwd[p][b] = (p/64)*64 + inv[p%64]
            const int e = e0 - NFWD;
            const int p = e >> 6, b0 = e & (NB - 1);
            const int base = p & ~(NCOLS - 1), pj = p & (NCOLS - 1);
            v.x = (float)(base + invcol(start_cols[b0 + 0], pj));
            v.y = (float)(base + invcol(start_cols[b0 + 1], pj));
            v.z = (float)(base + invcol(start_cols[b0 + 2], pj));
            v.w = (float)(base + invcol(start_cols[b0 + 3], pj));
        } else {                               // stripe_bounds: 64 starts, 64 ends
            const int e  = e0 - 2 * NFWD;      // 0..124, multiple of 4
            const int b0 = e & (NB - 1);
            const int add = (e < NB) ? 0 : SW;
            v.x = (float)(start_cols[b0 + 0] + add);
            v.y = (float)(start_cols[b0 + 1] + add);
            v.z = (float)(start_cols[b0 + 2] + add);
            v.w = (float)(start_cols[b0 + 3] + add);
        }
        idx4[f] = v;
    }
}

extern "C" void kernel_launch(void* const* d_in, const int* in_sizes, int n_in,
                              void* d_out, int out_size, void* d_ws, size_t ws_size,
                              hipStream_t stream) {
    const float4* patches    = (const float4*)d_in[0];
    const int*    start_cols = (const int*)d_in[1];
    float* out = (float*)d_out;

    patchshuffle_kernel<<<TOTAL_BLOCKS, 192, 0, stream>>>(patches, start_cols, out);
}